// Round 7
// baseline (84.814 us; speedup 1.0000x reference)
//
#include <hip/hip_runtime.h>
#include <hip/hip_bf16.h>
#include <math.h>

#define B_  8
#define C_  128
#define CH_ 64
#define LX_ 128
#define LY_ 1024

typedef __attribute__((ext_vector_type(8)))  _Float16 half8;
typedef __attribute__((ext_vector_type(16))) float f32x16;

// ---------------- K1: att = x^T @ W + b -> fp16 ; blocks 0..63 also prep wdTh -----
__global__ __launch_bounds__(128) void k1_att(
    const float* __restrict__ x, const float* __restrict__ y,
    const float* __restrict__ Wd, const float* __restrict__ bd,
    const float* __restrict__ Wp, const float* __restrict__ bp,
    const float* __restrict__ Wdown,
    _Float16* __restrict__ datt, _Float16* __restrict__ patt,
    _Float16* __restrict__ wdTh)
{
    const int blk = blockIdx.x;
    const int t = threadIdx.x;
    if (blk < 64) {                        // wdTh[kh][c] = (fp16) W_down[c][kh]
        int u = blk * 128 + t;
        wdTh[u] = (_Float16)Wdown[(u & 127) * CH_ + (u >> 7)];
    }
    const float* src; const float* W; const float* bias; _Float16* dst; int L;
    int b, l0;
    if (blk < 256) {
        int row0 = blk * 4; b = row0 >> 7; l0 = row0 & 127;
        src = x; W = Wd; bias = bd; dst = datt; L = LX_;
    } else {
        int row0 = (blk - 256) * 4; b = row0 >> 10; l0 = row0 & 1023;
        src = y; W = Wp; bias = bp; dst = patt; L = LY_;
    }
    __shared__ float col[4][128];
    {
        const float* sp = src + ((long)b * C_ + t) * L + l0;
        float4 v = *(const float4*)sp;
        col[0][t] = v.x; col[1][t] = v.y; col[2][t] = v.z; col[3][t] = v.w;
    }
    __syncthreads();
    float acc0 = bias[t], acc1 = acc0, acc2 = acc0, acc3 = acc0;
    #pragma unroll 8
    for (int c = 0; c < 128; ++c) {
        float w = W[c * 128 + t];
        float s0 = col[0][c], s1 = col[1][c], s2 = col[2][c], s3 = col[3][c];
        acc0 = fmaf(s0, w, acc0); acc1 = fmaf(s1, w, acc1);
        acc2 = fmaf(s2, w, acc2); acc3 = fmaf(s3, w, acc3);
    }
    _Float16* dp = dst + ((long)b * L + l0) * C_ + t;
    dp[0]      = (_Float16)acc0; dp[C_]     = (_Float16)acc1;
    dp[2 * C_] = (_Float16)acc2; dp[3 * C_] = (_Float16)acc3;
}

// ---------------- K2: 32x32x16 MFMA pair-GEMM, operands OFF the LDS pipe ----------
// block = (b, 32 lx, 32 ly), 4 waves. Wave (wl=w&1, wk=w>>1): lx rows [16wl,16wl+16),
// kh cols [32wk,32wk+32). d-slices read from GLOBAL (1 line/instr, L1-hot tile),
// pv/bf hoisted global->regs once. LDS only holds the block partials (17 KB).
__global__ __launch_bounds__(256, 3) void k2_main(
    const _Float16* __restrict__ datt, const _Float16* __restrict__ patt,
    const _Float16* __restrict__ wdTh, const float* __restrict__ bdown,
    float* __restrict__ HxP, float* __restrict__ HyP)
{
    const int b     = blockIdx.x >> 2;
    const int lxblk = blockIdx.x & 3;
    const int lyblk = blockIdx.y;
    const int t   = threadIdx.x;
    const int w   = t >> 6;
    const int wk  = w >> 1;     // kh half (0/1)
    const int wl  = w & 1;      // lx half (0/1)
    const int l   = t & 63;
    const int h   = l >> 5;     // k subgroup within MFMA operand
    const int c32 = l & 31;     // ly row for A/pv; kh col for B/D

    __shared__ float protH[32][66];
    __shared__ float compW[32][66];

    // ---- hoist p-fragments and B-fragments straight from global into regs ----
    const _Float16* prow = patt + ((long)(b * LY_) + lyblk * 32 + c32) * C_;
    const _Float16* wrow = wdTh + (wk * 32 + c32) * C_;
    half8 pv[8], bf[8];
    #pragma unroll
    for (int kt = 0; kt < 8; ++kt) {
        pv[kt] = *(const half8*)(prow + kt * 16 + h * 8);
        bf[kt] = *(const half8*)(wrow + kt * 16 + h * 8);
    }
    const float bdr = bdown[wk * 32 + c32];

    for (int u = t; u < 2112; u += 256) (&protH[0][0])[u] = 0.f;
    __syncthreads();

    // ---- main loop: 16 lx rows per wave; d from global (32B line, L1-hot) ----
    const _Float16* dbase = datt + ((long)(b * LX_) + lxblk * 32) * C_;
    const half8 hz = {};
    float hy[16];
    #pragma unroll
    for (int r = 0; r < 16; ++r) hy[r] = 0.f;

    #pragma unroll 1
    for (int lxr = 0; lxr < 16; ++lxr) {
        const int lxi = wl * 16 + lxr;
        const _Float16* drow = dbase + lxi * C_;
        half8 dv[8];
        #pragma unroll
        for (int kt = 0; kt < 8; ++kt)
            dv[kt] = *(const half8*)(drow + kt * 16 + h * 8);
        f32x16 acc;
        #pragma unroll
        for (int r = 0; r < 16; ++r) acc[r] = bdr;
        #pragma unroll
        for (int kt = 0; kt < 8; ++kt) {
            half8 s = __builtin_elementwise_max(dv[kt] + pv[kt], hz);
            acc = __builtin_amdgcn_mfma_f32_32x32x16_f16(s, bf[kt], acc, 0, 0, 0);
        }
        // D: col(kh)=wk*32+c32, row(ly)=(r&3)+8*(r>>2)+4h
        float pa[4] = {0.f, 0.f, 0.f, 0.f};
        #pragma unroll
        for (int r = 0; r < 16; ++r) {
            float v = fmaxf(acc[r], 0.f);
            hy[r] += v;
            pa[r & 3] += v;             // unroll-constant index -> registers
        }
        float sa = (pa[0] + pa[1]) + (pa[2] + pa[3]);
        sa += __shfl_xor(sa, 32);       // add other k-subgroup's 16 ly rows
        if (h == 0) compW[lxi][wk * 32 + c32] = sa;   // exclusive owner
    }

    // ---- combine Hy across wl-waves (LDS atomics, once per block) ----
    #pragma unroll
    for (int r = 0; r < 16; ++r) {
        int ly = (r & 3) + 8 * (r >> 2) + 4 * h;
        atomicAdd(&protH[ly][wk * 32 + c32], hy[r]);
    }
    __syncthreads();

    // ---- block partials -> global, plain coalesced stores ----
    {
        float* hxp = HxP + ((long)lyblk * (B_ * LX_) + b * LX_ + lxblk * 32) * 64;
        float* hyp = HyP + ((long)lxblk * (B_ * LY_) + b * LY_ + lyblk * 32) * 64;
        for (int u = t; u < 2048; u += 256) {
            int r = u >> 6, c = u & 63;
            hxp[u] = compW[r][c];
            hyp[u] = protH[r][c];
        }
    }
}

// ---------------- K3: sum partials -> (H*invN)@W_up + b_up -> gate -> out ---------
__global__ __launch_bounds__(256) void k3_gate(
    const float* __restrict__ HxP, const float* __restrict__ HyP,
    const float* __restrict__ wup, const float* __restrict__ bup,
    const float* __restrict__ x, const float* __restrict__ y,
    float* __restrict__ out)
{
    const int b = blockIdx.y;
    const int t = threadIdx.x;
    const float* part; const float* xin; float* outp; int L; float invN; int l0;
    int nq; long qstr;
    if (blockIdx.x < 4) {
        part = HxP; nq = 32; qstr = (long)B_ * LX_ * 64;
        xin = x; outp = out; L = LX_; invN = 1.f / 1024.f; l0 = blockIdx.x * 32;
    } else {
        part = HyP; nq = 4;  qstr = (long)B_ * LY_ * 64;
        xin = y; outp = out + (long)B_ * C_ * LX_; L = LY_; invN = 1.f / 128.f;
        l0 = (blockIdx.x - 4) * 32;
    }
    __shared__ float Ht[32][72];
    __shared__ float Wt[64][136];
    __shared__ float gg[32][133];

    const float* p0 = part + ((long)b * L + l0) * 64;
    for (int u = t; u < 2048; u += 256) {
        float a0 = 0.f, a1 = 0.f, a2 = 0.f, a3 = 0.f;
        #pragma unroll 4
        for (int q = 0; q < nq; q += 4) {
            a0 += p0[(long)q * qstr + u];
            a1 += p0[(long)(q + 1) * qstr + u];
            a2 += p0[(long)(q + 2) * qstr + u];
            a3 += p0[(long)(q + 3) * qstr + u];
        }
        Ht[u >> 6][u & 63] = (a0 + a1) + (a2 + a3);
    }
    #pragma unroll
    for (int i = 0; i < 8; ++i) {
        int idx = t + i * 256;                 // 2048 float4 = 64x128 floats
        int r = idx >> 5, c4 = (idx & 31) * 4;
        *(float4*)&Wt[r][c4] = *(const float4*)(wup + idx * 4);
    }
    __syncthreads();

    const int lrow = t >> 3, cg = (t & 7) * 4;  // c = cg + 32*jj + i
    float acc[4][4];
    #pragma unroll
    for (int jj = 0; jj < 4; ++jj)
        #pragma unroll
        for (int i = 0; i < 4; ++i) acc[jj][i] = 0.f;
    #pragma unroll 4
    for (int k = 0; k < 64; ++k) {
        float hv = Ht[lrow][k];
        #pragma unroll
        for (int jj = 0; jj < 4; ++jj) {
            float4 wv = *(const float4*)&Wt[k][cg + 32 * jj];
            acc[jj][0] = fmaf(hv, wv.x, acc[jj][0]);
            acc[jj][1] = fmaf(hv, wv.y, acc[jj][1]);
            acc[jj][2] = fmaf(hv, wv.z, acc[jj][2]);
            acc[jj][3] = fmaf(hv, wv.w, acc[jj][3]);
        }
    }
    #pragma unroll
    for (int jj = 0; jj < 4; ++jj)
        #pragma unroll
        for (int i = 0; i < 4; ++i) {
            int c = cg + 32 * jj + i;
            float v = fmaf(acc[jj][i], invN, bup[c]);
            float sg = 1.f / (1.f + expf(-v));
            gg[lrow][c] = sg * tanhf(v);
        }
    __syncthreads();
    for (int u = t; u < 4096; u += 256) {
        int c = u >> 5, li = u & 31;
        long idx = ((long)b * C_ + c) * L + l0 + li;
        outp[idx] = xin[idx] * (0.5f + gg[li][c]);
    }
}

extern "C" void kernel_launch(void* const* d_in, const int* in_sizes, int n_in,
                              void* d_out, int out_size, void* d_ws, size_t ws_size,
                              hipStream_t stream) {
    (void)in_sizes; (void)n_in; (void)out_size; (void)ws_size;
    const float* x     = (const float*)d_in[0];
    const float* y     = (const float*)d_in[1];
    const float* Wdrug = (const float*)d_in[2];
    const float* bdrug = (const float*)d_in[3];
    const float* Wprot = (const float*)d_in[4];
    const float* bprot = (const float*)d_in[5];
    const float* Wdown = (const float*)d_in[6];
    const float* bdown = (const float*)d_in[7];
    const float* Wup   = (const float*)d_in[8];
    const float* bup   = (const float*)d_in[9];
    float* out = (float*)d_out;
    char* ws = (char*)d_ws;

    _Float16* datt = (_Float16*)ws;                 // 131072 halves  (256 KB)
    _Float16* patt = (_Float16*)(ws + 262144);      // 1048576 halves (2 MB)
    _Float16* wdTh = (_Float16*)(ws + 2359296);     // 8192 halves    (16 KB)
    float*    HxP  = (float*)(ws + 2375680);        // 32*1024*64 f32 (8 MB)
    float*    HyP  = (float*)(ws + 10764288);       // 4*8192*64 f32  (8 MB)

    hipLaunchKernelGGL(k1_att, dim3(2304), dim3(128), 0, stream,
                       x, y, Wdrug, bdrug, Wprot, bprot, Wdown, datt, patt, wdTh);
    hipLaunchKernelGGL(k2_main, dim3(32, 32, 1), dim3(256), 0, stream,
                       datt, patt, wdTh, bdown, HxP, HyP);
    hipLaunchKernelGGL(k3_gate, dim3(36, 8), dim3(256), 0, stream,
                       HxP, HyP, Wup, bup, x, y, out);
}

// Round 8
// 84.044 us; speedup vs baseline: 1.0092x; 1.0092x over previous
//
#include <hip/hip_runtime.h>
#include <hip/hip_bf16.h>
#include <math.h>

#define B_  8
#define C_  128
#define CH_ 64
#define LX_ 128
#define LY_ 1024

typedef __attribute__((ext_vector_type(8)))  _Float16 half8;
typedef __attribute__((ext_vector_type(16))) float f32x16;

// ---------------- K1: att = x^T @ W + b -> fp16 ; blocks 0..63 also prep wdTh -----
__global__ __launch_bounds__(128) void k1_att(
    const float* __restrict__ x, const float* __restrict__ y,
    const float* __restrict__ Wd, const float* __restrict__ bd,
    const float* __restrict__ Wp, const float* __restrict__ bp,
    const float* __restrict__ Wdown,
    _Float16* __restrict__ datt, _Float16* __restrict__ patt,
    _Float16* __restrict__ wdTh)
{
    const int blk = blockIdx.x;
    const int t = threadIdx.x;
    if (blk < 64) {                        // wdTh[kh][c] = (fp16) W_down[c][kh]
        int u = blk * 128 + t;
        wdTh[u] = (_Float16)Wdown[(u & 127) * CH_ + (u >> 7)];
    }
    const float* src; const float* W; const float* bias; _Float16* dst; int L;
    int b, l0;
    if (blk < 256) {
        int row0 = blk * 4; b = row0 >> 7; l0 = row0 & 127;
        src = x; W = Wd; bias = bd; dst = datt; L = LX_;
    } else {
        int row0 = (blk - 256) * 4; b = row0 >> 10; l0 = row0 & 1023;
        src = y; W = Wp; bias = bp; dst = patt; L = LY_;
    }
    __shared__ float col[4][128];
    {
        const float* sp = src + ((long)b * C_ + t) * L + l0;
        float4 v = *(const float4*)sp;
        col[0][t] = v.x; col[1][t] = v.y; col[2][t] = v.z; col[3][t] = v.w;
    }
    __syncthreads();
    float acc0 = bias[t], acc1 = acc0, acc2 = acc0, acc3 = acc0;
    #pragma unroll 8
    for (int c = 0; c < 128; ++c) {
        float w = W[c * 128 + t];
        float s0 = col[0][c], s1 = col[1][c], s2 = col[2][c], s3 = col[3][c];
        acc0 = fmaf(s0, w, acc0); acc1 = fmaf(s1, w, acc1);
        acc2 = fmaf(s2, w, acc2); acc3 = fmaf(s3, w, acc3);
    }
    _Float16* dp = dst + ((long)b * L + l0) * C_ + t;
    dp[0]      = (_Float16)acc0; dp[C_]     = (_Float16)acc1;
    dp[2 * C_] = (_Float16)acc2; dp[3 * C_] = (_Float16)acc3;
}

// ---------------- K2: 32x32x16 MFMA, kt-outer ROW-PAIR loop (indep chains) --------
// block = (b, 32 lx, 32 ly), 4 waves. Wave (wl=w&1, wk=w>>1): lx rows [16wl,16wl+16)
// in pairs, kh cols [32wk,32wk+32). Per kt-step: 2 INDEPENDENT MFMAs (rows a,b) ->
// dependent-use distance ~40cyc instead of back-to-back. LB(256,4): grid 1024 =
// exactly 4 blocks/CU (no tail), 4 waves/SIMD. Regs ~125 <= 128 cap (audited).
__global__ __launch_bounds__(256, 4) void k2_main(
    const _Float16* __restrict__ datt, const _Float16* __restrict__ patt,
    const _Float16* __restrict__ wdTh, const float* __restrict__ bdown,
    float* __restrict__ HxP, float* __restrict__ HyP)
{
    const int b     = blockIdx.x >> 2;
    const int lxblk = blockIdx.x & 3;
    const int lyblk = blockIdx.y;
    const int t   = threadIdx.x;
    const int w   = t >> 6;
    const int wk  = w >> 1;     // kh half (0/1)
    const int wl  = w & 1;      // lx half (0/1)
    const int l   = t & 63;
    const int h   = l >> 5;     // k subgroup within MFMA operand
    const int c32 = l & 31;     // ly row for A/pv; kh col for B/D

    __shared__ _Float16 dTh[32][136];   // 8.7 KB d-tile (2-addr broadcast reads)
    __shared__ float protH[32][66];
    __shared__ float compW[32][66];     // total ~25.6 KB -> 4 blocks/CU fits

    // ---- stage d-tile, zero partials ----
    {
        const _Float16* dsrc = datt + ((long)(b * LX_) + lxblk * 32) * C_;
        int idx = t;
        #pragma unroll
        for (int i = 0; i < 2; ++i, idx += 256) {
            int r = idx >> 4, c = (idx & 15) * 8;
            *(half8*)&dTh[r][c] = *(const half8*)(dsrc + r * C_ + c);
        }
        for (int u = t; u < 4224; u += 256) (&protH[0][0])[u] = 0.f;
    }

    // ---- hoist p-fragments and B-fragments from global into regs ----
    const _Float16* prow = patt + ((long)(b * LY_) + lyblk * 32 + c32) * C_;
    const _Float16* wrow = wdTh + (wk * 32 + c32) * C_;
    half8 pv[8], bf[8];
    #pragma unroll
    for (int kt = 0; kt < 8; ++kt) {
        pv[kt] = *(const half8*)(prow + kt * 16 + h * 8);
        bf[kt] = *(const half8*)(wrow + kt * 16 + h * 8);
    }
    const float bdr = bdown[wk * 32 + c32];
    __syncthreads();

    // ---- main loop: 8 row-pairs, kt-outer, 2 independent MFMA chains ----
    const half8 hz = {};
    float hy[16];
    #pragma unroll
    for (int r = 0; r < 16; ++r) hy[r] = 0.f;

    #pragma unroll 1
    for (int lxp = 0; lxp < 8; ++lxp) {
        const int lxa = wl * 16 + lxp * 2;
        f32x16 accA = {}, accB = {};
        #pragma unroll
        for (int kt = 0; kt < 8; ++kt) {
            half8 dva = *(const half8*)&dTh[lxa][kt * 16 + h * 8];
            half8 dvb = *(const half8*)&dTh[lxa + 1][kt * 16 + h * 8];
            half8 sa = __builtin_elementwise_max(dva + pv[kt], hz);
            half8 sb = __builtin_elementwise_max(dvb + pv[kt], hz);
            accA = __builtin_amdgcn_mfma_f32_32x32x16_f16(sa, bf[kt], accA, 0, 0, 0);
            accB = __builtin_amdgcn_mfma_f32_32x32x16_f16(sb, bf[kt], accB, 0, 0, 0);
        }
        // D: col(kh)=wk*32+c32, row(ly)=(r&3)+8*(r>>2)+4h ; bias folded here
        float pa[4] = {0.f, 0.f, 0.f, 0.f}, pb[4] = {0.f, 0.f, 0.f, 0.f};
        #pragma unroll
        for (int r = 0; r < 16; ++r) {
            float va = fmaxf(accA[r] + bdr, 0.f);
            float vb = fmaxf(accB[r] + bdr, 0.f);
            hy[r] += va + vb;
            pa[r & 3] += va;            // unroll-constant index -> registers
            pb[r & 3] += vb;
        }
        float sa2 = (pa[0] + pa[1]) + (pa[2] + pa[3]);
        float sb2 = (pb[0] + pb[1]) + (pb[2] + pb[3]);
        sa2 += __shfl_xor(sa2, 32);     // add other k-subgroup's 16 ly rows
        sb2 += __shfl_xor(sb2, 32);
        if (h == 0) {                   // exclusive owner: plain LDS writes
            compW[lxa][wk * 32 + c32]     = sa2;
            compW[lxa + 1][wk * 32 + c32] = sb2;
        }
    }

    // ---- combine Hy across wl-waves (LDS atomics, once per block) ----
    #pragma unroll
    for (int r = 0; r < 16; ++r) {
        int ly = (r & 3) + 8 * (r >> 2) + 4 * h;
        atomicAdd(&protH[ly][wk * 32 + c32], hy[r]);
    }
    __syncthreads();

    // ---- block partials -> global, plain coalesced stores ----
    {
        float* hxp = HxP + ((long)lyblk * (B_ * LX_) + b * LX_ + lxblk * 32) * 64;
        float* hyp = HyP + ((long)lxblk * (B_ * LY_) + b * LY_ + lyblk * 32) * 64;
        for (int u = t; u < 2048; u += 256) {
            int r = u >> 6, c = u & 63;
            hxp[u] = compW[r][c];
            hyp[u] = protH[r][c];
        }
    }
}

// ---------------- K3: sum partials -> (H*invN)@W_up + b_up -> gate -> out ---------
__global__ __launch_bounds__(256) void k3_gate(
    const float* __restrict__ HxP, const float* __restrict__ HyP,
    const float* __restrict__ wup, const float* __restrict__ bup,
    const float* __restrict__ x, const float* __restrict__ y,
    float* __restrict__ out)
{
    const int b = blockIdx.y;
    const int t = threadIdx.x;
    const float* part; const float* xin; float* outp; int L; float invN; int l0;
    int nq; long qstr;
    if (blockIdx.x < 4) {
        part = HxP; nq = 32; qstr = (long)B_ * LX_ * 64;
        xin = x; outp = out; L = LX_; invN = 1.f / 1024.f; l0 = blockIdx.x * 32;
    } else {
        part = HyP; nq = 4;  qstr = (long)B_ * LY_ * 64;
        xin = y; outp = out + (long)B_ * C_ * LX_; L = LY_; invN = 1.f / 128.f;
        l0 = (blockIdx.x - 4) * 32;
    }
    __shared__ float Ht[32][72];
    __shared__ float Wt[64][136];
    __shared__ float gg[32][133];

    const float* p0 = part + ((long)b * L + l0) * 64;
    for (int u = t; u < 2048; u += 256) {
        float a0 = 0.f, a1 = 0.f, a2 = 0.f, a3 = 0.f;
        #pragma unroll 4
        for (int q = 0; q < nq; q += 4) {
            a0 += p0[(long)q * qstr + u];
            a1 += p0[(long)(q + 1) * qstr + u];
            a2 += p0[(long)(q + 2) * qstr + u];
            a3 += p0[(long)(q + 3) * qstr + u];
        }
        Ht[u >> 6][u & 63] = (a0 + a1) + (a2 + a3);
    }
    #pragma unroll
    for (int i = 0; i < 8; ++i) {
        int idx = t + i * 256;                 // 2048 float4 = 64x128 floats
        int r = idx >> 5, c4 = (idx & 31) * 4;
        *(float4*)&Wt[r][c4] = *(const float4*)(wup + idx * 4);
    }
    __syncthreads();

    const int lrow = t >> 3, cg = (t & 7) * 4;  // c = cg + 32*jj + i
    float acc[4][4];
    #pragma unroll
    for (int jj = 0; jj < 4; ++jj)
        #pragma unroll
        for (int i = 0; i < 4; ++i) acc[jj][i] = 0.f;
    #pragma unroll 4
    for (int k = 0; k < 64; ++k) {
        float hv = Ht[lrow][k];
        #pragma unroll
        for (int jj = 0; jj < 4; ++jj) {
            float4 wv = *(const float4*)&Wt[k][cg + 32 * jj];
            acc[jj][0] = fmaf(hv, wv.x, acc[jj][0]);
            acc[jj][1] = fmaf(hv, wv.y, acc[jj][1]);
            acc[jj][2] = fmaf(hv, wv.z, acc[jj][2]);
            acc[jj][3] = fmaf(hv, wv.w, acc[jj][3]);
        }
    }
    #pragma unroll
    for (int jj = 0; jj < 4; ++jj)
        #pragma unroll
        for (int i = 0; i < 4; ++i) {
            int c = cg + 32 * jj + i;
            float v = fmaf(acc[jj][i], invN, bup[c]);
            float sg = 1.f / (1.f + expf(-v));
            gg[lrow][c] = sg * tanhf(v);
        }
    __syncthreads();
    for (int u = t; u < 4096; u += 256) {
        int c = u >> 5, li = u & 31;
        long idx = ((long)b * C_ + c) * L + l0 + li;
        outp[idx] = xin[idx] * (0.5f + gg[li][c]);
    }
}

extern "C" void kernel_launch(void* const* d_in, const int* in_sizes, int n_in,
                              void* d_out, int out_size, void* d_ws, size_t ws_size,
                              hipStream_t stream) {
    (void)in_sizes; (void)n_in; (void)out_size; (void)ws_size;
    const float* x     = (const float*)d_in[0];
    const float* y     = (const float*)d_in[1];
    const float* Wdrug = (const float*)d_in[2];
    const float* bdrug = (const float*)d_in[3];
    const float* Wprot = (const float*)d_in[4];
    const float* bprot = (const float*)d_in[5];
    const float* Wdown = (const float*)d_in[6];
    const float* bdown = (const float*)d_in[7];
    const float* Wup   = (const float*)d_in[8];
    const float* bup   = (const float*)d_in[9];
    float* out = (float*)d_out;
    char* ws = (char*)d_ws;

    _Float16* datt = (_Float16*)ws;                 // 131072 halves  (256 KB)
    _Float16* patt = (_Float16*)(ws + 262144);      // 1048576 halves (2 MB)
    _Float16* wdTh = (_Float16*)(ws + 2359296);     // 8192 halves    (16 KB)
    float*    HxP  = (float*)(ws + 2375680);        // 32*1024*64 f32 (8 MB)
    float*    HyP  = (float*)(ws + 10764288);       // 4*8192*64 f32  (8 MB)

    hipLaunchKernelGGL(k1_att, dim3(2304), dim3(128), 0, stream,
                       x, y, Wdrug, bdrug, Wprot, bprot, Wdown, datt, patt, wdTh);
    hipLaunchKernelGGL(k2_main, dim3(32, 32, 1), dim3(256), 0, stream,
                       datt, patt, wdTh, bdown, HxP, HyP);
    hipLaunchKernelGGL(k3_gate, dim3(36, 8), dim3(256), 0, stream,
                       HxP, HyP, Wup, bup, x, y, out);
}

// Round 9
// 71.316 us; speedup vs baseline: 1.1893x; 1.1785x over previous
//
#include <hip/hip_runtime.h>
#include <hip/hip_bf16.h>
#include <math.h>

#define B_  8
#define C_  128
#define CH_ 64
#define LX_ 128
#define LY_ 1024

typedef __attribute__((ext_vector_type(8)))  _Float16 half8;
typedef __attribute__((ext_vector_type(16))) float f32x16;

// ---------------- K1: att = x^T @ W + b -> fp16 ; blocks 0..63 also prep wdTh -----
__global__ __launch_bounds__(128) void k1_att(
    const float* __restrict__ x, const float* __restrict__ y,
    const float* __restrict__ Wd, const float* __restrict__ bd,
    const float* __restrict__ Wp, const float* __restrict__ bp,
    const float* __restrict__ Wdown,
    _Float16* __restrict__ datt, _Float16* __restrict__ patt,
    _Float16* __restrict__ wdTh)
{
    const int blk = blockIdx.x;
    const int t = threadIdx.x;
    if (blk < 64) {                        // wdTh[kh][c] = (fp16) W_down[c][kh]
        int u = blk * 128 + t;
        wdTh[u] = (_Float16)Wdown[(u & 127) * CH_ + (u >> 7)];
    }
    const float* src; const float* W; const float* bias; _Float16* dst; int L;
    int b, l0;
    if (blk < 256) {
        int row0 = blk * 4; b = row0 >> 7; l0 = row0 & 127;
        src = x; W = Wd; bias = bd; dst = datt; L = LX_;
    } else {
        int row0 = (blk - 256) * 4; b = row0 >> 10; l0 = row0 & 1023;
        src = y; W = Wp; bias = bp; dst = patt; L = LY_;
    }
    __shared__ float col[4][128];
    {
        const float* sp = src + ((long)b * C_ + t) * L + l0;
        float4 v = *(const float4*)sp;
        col[0][t] = v.x; col[1][t] = v.y; col[2][t] = v.z; col[3][t] = v.w;
    }
    __syncthreads();
    float acc0 = bias[t], acc1 = acc0, acc2 = acc0, acc3 = acc0;
    #pragma unroll 8
    for (int c = 0; c < 128; ++c) {
        float w = W[c * 128 + t];
        float s0 = col[0][c], s1 = col[1][c], s2 = col[2][c], s3 = col[3][c];
        acc0 = fmaf(s0, w, acc0); acc1 = fmaf(s1, w, acc1);
        acc2 = fmaf(s2, w, acc2); acc3 = fmaf(s3, w, acc3);
    }
    _Float16* dp = dst + ((long)b * L + l0) * C_ + t;
    dp[0]      = (_Float16)acc0; dp[C_]     = (_Float16)acc1;
    dp[2 * C_] = (_Float16)acc2; dp[3 * C_] = (_Float16)acc3;
}

// ---------------- K2: 32x32x16 MFMA; NO shfl, NO atomics, NO divergence -----------
// block = (b, 32 lx, 32 ly), 4 waves. Wave (wl=w&1, wk=w>>1): lx rows [16wl,16wl+16)
// in pairs (2 indep MFMA chains), kh cols [32wk,32wk+32).
// Loop body: global d-load -> pk VALU -> MFMA -> per-lane readout -> 2 plain
// ds_write_b32. Hx h-combine + Hy wl-combine deferred to a plain-read epilogue.
__global__ __launch_bounds__(256, 3) void k2_main(
    const _Float16* __restrict__ datt, const _Float16* __restrict__ patt,
    const _Float16* __restrict__ wdTh, const float* __restrict__ bdown,
    float* __restrict__ HxP, float* __restrict__ HyP)
{
    const int b     = blockIdx.x >> 2;
    const int lxblk = blockIdx.x & 3;
    const int lyblk = blockIdx.y;
    const int t   = threadIdx.x;
    const int w   = t >> 6;
    const int wk  = w >> 1;     // kh half (0/1)
    const int wl  = w & 1;      // lx half (0/1)
    const int l   = t & 63;
    const int h   = l >> 5;     // k subgroup within MFMA operand
    const int c32 = l & 31;     // ly row for A/pv; kh col for B/D

    __shared__ float compWp[32][2][66];   // [lx][h][kh] partials, every slot written
    __shared__ float protP[2][32][66];    // [wl][ly][kh] partials, every slot written

    // ---- hoist p-fragments and B-fragments from global into regs ----
    const _Float16* prow = patt + ((long)(b * LY_) + lyblk * 32 + c32) * C_;
    const _Float16* wrow = wdTh + (wk * 32 + c32) * C_;
    half8 pv[8], bf[8];
    #pragma unroll
    for (int kt = 0; kt < 8; ++kt) {
        pv[kt] = *(const half8*)(prow + kt * 16 + h * 8);
        bf[kt] = *(const half8*)(wrow + kt * 16 + h * 8);
    }
    const float bdr = bdown[wk * 32 + c32];

    const _Float16* dbase = datt + ((long)(b * LX_) + lxblk * 32) * C_;
    const half8 hz = {};
    float hy[16];
    #pragma unroll
    for (int r = 0; r < 16; ++r) hy[r] = 0.f;

    // ---- main loop: 8 row-pairs; nothing cross-lane, nothing atomic ----
    #pragma unroll 1
    for (int lxp = 0; lxp < 8; ++lxp) {
        const int lxa = wl * 16 + lxp * 2;
        const _Float16* da = dbase + lxa * C_ + h * 8;
        f32x16 accA = {}, accB = {};
        #pragma unroll
        for (int kt = 0; kt < 8; ++kt) {
            half8 dva = *(const half8*)(da + kt * 16);
            half8 dvb = *(const half8*)(da + C_ + kt * 16);
            half8 sa = __builtin_elementwise_max(dva + pv[kt], hz);
            half8 sb = __builtin_elementwise_max(dvb + pv[kt], hz);
            accA = __builtin_amdgcn_mfma_f32_32x32x16_f16(sa, bf[kt], accA, 0, 0, 0);
            accB = __builtin_amdgcn_mfma_f32_32x32x16_f16(sb, bf[kt], accB, 0, 0, 0);
        }
        // D: col(kh)=wk*32+c32, row(ly)=(r&3)+8*(r>>2)+4h ; bias folded here
        float sA = 0.f, sB = 0.f;
        #pragma unroll
        for (int r = 0; r < 16; ++r) {
            float va = fmaxf(accA[r] + bdr, 0.f);
            float vb = fmaxf(accB[r] + bdr, 0.f);
            hy[r] += va + vb;
            sA += va; sB += vb;
        }
        // plain per-lane LDS writes (2-way bank alias = free); owner-exclusive
        compWp[lxa][h][wk * 32 + c32]     = sA;
        compWp[lxa + 1][h][wk * 32 + c32] = sB;
    }

    // ---- Hy partials: 16 plain writes per lane (owner-exclusive) ----
    #pragma unroll
    for (int r = 0; r < 16; ++r) {
        int ly = (r & 3) + 8 * (r >> 2) + 4 * h;
        protP[wl][ly][wk * 32 + c32] = hy[r];
    }
    __syncthreads();

    // ---- epilogue: h-combine / wl-combine with plain reads, coalesced stores ----
    {
        float* hxp = HxP + ((long)lyblk * (B_ * LX_) + b * LX_ + lxblk * 32) * 64;
        float* hyp = HyP + ((long)lxblk * (B_ * LY_) + b * LY_ + lyblk * 32) * 64;
        for (int u = t; u < 2048; u += 256) {
            int r = u >> 6, c = u & 63;
            hxp[u] = compWp[r][0][c] + compWp[r][1][c];
            hyp[u] = protP[0][r][c] + protP[1][r][c];
        }
    }
}

// ---------------- K3: sum partials -> (H*invN)@W_up + b_up -> gate -> out ---------
__global__ __launch_bounds__(256) void k3_gate(
    const float* __restrict__ HxP, const float* __restrict__ HyP,
    const float* __restrict__ wup, const float* __restrict__ bup,
    const float* __restrict__ x, const float* __restrict__ y,
    float* __restrict__ out)
{
    const int b = blockIdx.y;
    const int t = threadIdx.x;
    const float* part; const float* xin; float* outp; int L; float invN; int l0;
    int nq; long qstr;
    if (blockIdx.x < 4) {
        part = HxP; nq = 32; qstr = (long)B_ * LX_ * 64;
        xin = x; outp = out; L = LX_; invN = 1.f / 1024.f; l0 = blockIdx.x * 32;
    } else {
        part = HyP; nq = 4;  qstr = (long)B_ * LY_ * 64;
        xin = y; outp = out + (long)B_ * C_ * LX_; L = LY_; invN = 1.f / 128.f;
        l0 = (blockIdx.x - 4) * 32;
    }
    __shared__ float Ht[32][72];
    __shared__ float Wt[64][136];
    __shared__ float gg[32][133];

    const float* p0 = part + ((long)b * L + l0) * 64;
    for (int u = t; u < 2048; u += 256) {
        float a0 = 0.f, a1 = 0.f, a2 = 0.f, a3 = 0.f;
        #pragma unroll 4
        for (int q = 0; q < nq; q += 4) {
            a0 += p0[(long)q * qstr + u];
            a1 += p0[(long)(q + 1) * qstr + u];
            a2 += p0[(long)(q + 2) * qstr + u];
            a3 += p0[(long)(q + 3) * qstr + u];
        }
        Ht[u >> 6][u & 63] = (a0 + a1) + (a2 + a3);
    }
    #pragma unroll
    for (int i = 0; i < 8; ++i) {
        int idx = t + i * 256;                 // 2048 float4 = 64x128 floats
        int r = idx >> 5, c4 = (idx & 31) * 4;
        *(float4*)&Wt[r][c4] = *(const float4*)(wup + idx * 4);
    }
    __syncthreads();

    const int lrow = t >> 3, cg = (t & 7) * 4;  // c = cg + 32*jj + i
    float acc[4][4];
    #pragma unroll
    for (int jj = 0; jj < 4; ++jj)
        #pragma unroll
        for (int i = 0; i < 4; ++i) acc[jj][i] = 0.f;
    #pragma unroll 4
    for (int k = 0; k < 64; ++k) {
        float hv = Ht[lrow][k];
        #pragma unroll
        for (int jj = 0; jj < 4; ++jj) {
            float4 wv = *(const float4*)&Wt[k][cg + 32 * jj];
            acc[jj][0] = fmaf(hv, wv.x, acc[jj][0]);
            acc[jj][1] = fmaf(hv, wv.y, acc[jj][1]);
            acc[jj][2] = fmaf(hv, wv.z, acc[jj][2]);
            acc[jj][3] = fmaf(hv, wv.w, acc[jj][3]);
        }
    }
    #pragma unroll
    for (int jj = 0; jj < 4; ++jj)
        #pragma unroll
        for (int i = 0; i < 4; ++i) {
            int c = cg + 32 * jj + i;
            float v = fmaf(acc[jj][i], invN, bup[c]);
            float sg = 1.f / (1.f + expf(-v));
            gg[lrow][c] = sg * tanhf(v);
        }
    __syncthreads();
    for (int u = t; u < 4096; u += 256) {
        int c = u >> 5, li = u & 31;
        long idx = ((long)b * C_ + c) * L + l0 + li;
        outp[idx] = xin[idx] * (0.5f + gg[li][c]);
    }
}

extern "C" void kernel_launch(void* const* d_in, const int* in_sizes, int n_in,
                              void* d_out, int out_size, void* d_ws, size_t ws_size,
                              hipStream_t stream) {
    (void)in_sizes; (void)n_in; (void)out_size; (void)ws_size;
    const float* x     = (const float*)d_in[0];
    const float* y     = (const float*)d_in[1];
    const float* Wdrug = (const float*)d_in[2];
    const float* bdrug = (const float*)d_in[3];
    const float* Wprot = (const float*)d_in[4];
    const float* bprot = (const float*)d_in[5];
    const float* Wdown = (const float*)d_in[6];
    const float* bdown = (const float*)d_in[7];
    const float* Wup   = (const float*)d_in[8];
    const float* bup   = (const float*)d_in[9];
    float* out = (float*)d_out;
    char* ws = (char*)d_ws;

    _Float16* datt = (_Float16*)ws;                 // 131072 halves  (256 KB)
    _Float16* patt = (_Float16*)(ws + 262144);      // 1048576 halves (2 MB)
    _Float16* wdTh = (_Float16*)(ws + 2359296);     // 8192 halves    (16 KB)
    float*    HxP  = (float*)(ws + 2375680);        // 32*1024*64 f32 (8 MB)
    float*    HyP  = (float*)(ws + 10764288);       // 4*8192*64 f32  (8 MB)

    hipLaunchKernelGGL(k1_att, dim3(2304), dim3(128), 0, stream,
                       x, y, Wdrug, bdrug, Wprot, bprot, Wdown, datt, patt, wdTh);
    hipLaunchKernelGGL(k2_main, dim3(32, 32, 1), dim3(256), 0, stream,
                       datt, patt, wdTh, bdown, HxP, HyP);
    hipLaunchKernelGGL(k3_gate, dim3(36, 8), dim3(256), 0, stream,
                       HxP, HyP, Wup, bup, x, y, out);
}